// Round 11
// baseline (104.818 us; speedup 1.0000x reference)
//
#include <hip/hip_runtime.h>
#include <math.h>

#define B_    256
#define C_    22
#define T_    1000
#define NB_   6
#define E_    6
#define MNB_  48
#define POOL_ 125
#define TP_   8
#define NC_   9
#define FEAT_ 384   // MNB_*TP_

#define PQ_   352    // plane length; x[m] lives at (plane (m+24)%3, q (m+24)/3)
#define NTH   768
#define CH_   11     // channels per staging half

// Load 4 aligned float4 (16 floats) from plane pp at element base 4*tile+Aoff.
#define LOADP(F, pp, Aoff)                                                   \
    {                                                                        \
        const float4* pb = (const float4*)&bw[pp][4*tile + (Aoff)];          \
        float4 q0 = pb[0], q1 = pb[1], q2 = pb[2], q3 = pb[3];               \
        *(float4*)&F[0]  = q0; *(float4*)&F[4]  = q1;                        \
        *(float4*)&F[8]  = q2; *(float4*)&F[12] = q3;                        \
    }

// Apply single-nb taps ck[] to window F.
#define TAPS(F, idx0, j0, nj)                                                \
    _Pragma("unroll")                                                        \
    for (int a = 0; a < (nj); ++a) {                                         \
        const float cj = ck[(j0) + 3*a];                                     \
        s0 = fmaf(cj, F[(idx0) + a    ], s0);                                \
        s1 = fmaf(cj, F[(idx0) + a + 1], s1);                                \
        s2 = fmaf(cj, F[(idx0) + a + 2], s2);                                \
        s3 = fmaf(cj, F[(idx0) + a + 3], s3);                                \
    }

// ---------------------------------------------------------------------------
// Stage 1 (R11): grid 512 = (b, nb-triple). 768 threads, single-nb per
// thread (29 taps -> ~61 VGPR demand, NO spill at the compiler's 84), LDS
// ~64 KB -> 2 blocks/CU resident = 6 waves/SIMD (grid > #CUs makes it real).
// Channel-halved staging (11 ch planes), ck re-gathered per half so nothing
// big lives across staging. Outputs hp (B,48) + gm (B,6) to ws.
// ---------------------------------------------------------------------------
__global__ __launch_bounds__(NTH) void fb_stage1(
    const float* __restrict__ x,
    const float* __restrict__ fir,
    const float* __restrict__ w3,
    const float* __restrict__ w5,
    const float* __restrict__ w7,
    const float* __restrict__ bn_g, const float* __restrict__ bn_b,
    const float* __restrict__ bn_m, const float* __restrict__ bn_v,
    const float* __restrict__ sconv_w,
    float* __restrict__ hp, float* __restrict__ gm)
{
    const int b   = blockIdx.x >> 1;
    const int g   = blockIdx.x & 1;
    const int nbb = 3 * g;                  // this block's nb base (3 bands)
    const int tid = threadIdx.x;

    __shared__ __align__(16) float pl[CH_][3][PQ_];  // 46.5 KB
    __shared__ __align__(16) float hrow[3][T_];      // 12 KB
    __shared__ float firs3[3][21];
    __shared__ float w3s3[3][3];
    __shared__ float w5s3[3][5];
    __shared__ float w7s3[3][7];
    __shared__ float sws3[3][C_];
    __shared__ float sbn3[3][2];
    __shared__ float ckl[3][3][29];      // [region][local nb][tap]
    __shared__ float xbv[3][CH_][13];    // xb(0..6), xb(994..999) per (ln,cl)
    __shared__ float term[3][6][C_];
    __shared__ float corr[3][6];
    __shared__ float psum[24];

    const float* xbase = x + (size_t)b * (C_ * T_);

    // ---- weights to LDS (3 local bands only) ----
    if (tid < 63)                      { int ln=tid/21; firs3[ln][tid%21] = fir[(nbb+ln)*21 + tid%21]; }
    else if (tid >= 64  && tid < 73)   { int k=tid-64;  w3s3[k/3][k%3] = w3[(nbb + k/3)*3 + k%3]; }
    else if (tid >= 96  && tid < 111)  { int k=tid-96;  w5s3[k/5][k%5] = w5[(nbb + k/5)*5 + k%5]; }
    else if (tid >= 128 && tid < 149)  { int k=tid-128; w7s3[k/7][k%7] = w7[(nbb + k/7)*7 + k%7]; }
    else if (tid >= 160 && tid < 226)  { int k=tid-160; sws3[k/C_][k%C_] = sconv_w[(nbb + k/C_)*C_ + k%C_]; }
    else if (tid >= 256 && tid < 259) {
        const int ln = tid - 256, nb = nbb + ln;
        float sc = bn_g[nb] * rsqrtf(bn_v[nb] + 1e-5f);
        sbn3[ln][0] = sc * (1.f/3.f);       // folds the /3 of the triple-mean
        sbn3[ln][1] = bn_b[nb] - bn_m[nb] * sc;
    }

    // ---- wave-uniform region decomposition (region per 4-wave group) ----
    const int rr = tid >> 8;                // region 0,1,2
    const int j  = tid & 255;
    int ln = 0, tile = 0;
    bool act = false;
    if (rr == 0)      { act = (j < 249); ln = j / 83; tile = j % 83; }
    else if (rr == 1) { act = (j < 252); ln = j / 84; tile = 83 + j % 84; }
    else              { act = (j < 249); ln = j / 83; tile = 167 + j % 83; }

    float acc0 = 0.f, acc1 = 0.f, acc2 = 0.f, acc3 = 0.f;

    #pragma unroll 1
    for (int h = 0; h < 2; ++h) {
        // ---- stage half h: 11 channels in plane order ----
        #pragma unroll
        for (int k = 0; k < 4; ++k) {
            const int idx = tid + k * NTH;            // 0..3071
            if (idx < CH_ * 264) {                    // 2904
                const int cl  = idx / 264;
                const int rem = idx % 264;
                const int p   = rem / 88;
                const int q0  = (rem % 88) * 4;
                const float* xr = xbase + (h * CH_ + cl) * T_;
                float v[4];
                #pragma unroll
                for (int i = 0; i < 4; ++i) {
                    const int m  = 3 * (q0 + i) + p - 24;
                    const int mc = m < 0 ? 0 : (m > 999 ? 999 : m);
                    const float val = xr[mc];
                    v[i] = ((unsigned)m < 1000u) ? val : 0.f;
                }
                *(float4*)&pl[cl][p][q0] = make_float4(v[0], v[1], v[2], v[3]);
            }
        }
        __syncthreads();   // S1

        // ---- (h==0) build ckl ∥ phaseB: boundary FIR dots for this half ----
        if (h == 0 && tid < 261) {                    // 9 combos * 29 taps
            const int combo = tid / 29, jj = tid % 29;
            const int rr2 = combo / 3, lnn = combo % 3;
            const float* wk = (rr2 == 0) ? w3s3[lnn] : (rr2 == 1 ? w5s3[lnn] : w7s3[lnn]);
            const int K  = (rr2 == 0) ? 3 : (rr2 == 1 ? 5 : 7);
            const int pk = K >> 1;
            float s = 0.f;
            #pragma unroll
            for (int oi = 0; oi < 9; ++oi) {
                const int o = oi - 3;
                float we = 0.f;
                for (int k = 0; k < 7; ++k) {
                    if (k < K) {
                        const int jx = o + pk - k;
                        if (jx >= 0 && jx < 3) we += wk[k];
                    }
                }
                const int i = jj - oi;
                if (i >= 0 && i < 21) s = fmaf(we, firs3[lnn][i], s);
            }
            ckl[rr2][lnn][jj] = s;
        }
        if (tid < 3 * CH_ * 13) {                     // 429
            const int lnn = tid / (CH_ * 13);
            const int rem = tid % (CH_ * 13);
            const int cl  = rem / 13, pos = rem % 13;
            const int m   = (pos < 7) ? pos : (987 + pos);     // 0..6, 994..999
            int mm = m + 14;                                   // (m-10)+24
            int q  = mm / 3, p = mm - 3 * q;
            float s = 0.f;
            #pragma unroll
            for (int i = 0; i < 21; ++i) {
                s = fmaf(firs3[lnn][i], pl[cl][p][q], s);
                ++p; if (p == 3) { p = 0; ++q; }
            }
            xbv[lnn][cl][pos] = s;
        }
        __syncthreads();   // S2

        // ---- phaseC: exact special outputs t in {0,332,333,666,667,999} ----
        if (tid < 3 * 6 * CH_) {                      // 198
            const int lnn = tid / (6 * CH_);
            const int rem = tid % (6 * CH_);
            const int tix = rem / CH_, cl = rem % CH_;
            const float* X  = xbv[lnn][cl];  // X[0..6]=xb(0..6), X[7..12]=xb(994..999)
            const float* W3 = w3s3[lnn];
            const float* W5 = w5s3[lnn];
            const float* W7 = w7s3[lnn];
            float s;
            switch (tix) {
            case 0:
                s = W3[1]*X[0]+W3[2]*X[1]
                  + W3[0]*X[0]+W3[1]*X[1]+W3[2]*X[2]
                  + W3[0]*X[1]+W3[1]*X[2]+W3[2]*X[3];
                break;
            case 1:
                s = W3[0]*X[8]+W3[1]*X[9]+W3[2]*X[10]
                  + W3[0]*X[9]+W3[1]*X[10]+W3[2]*X[11]
                  + W3[0]*X[10]+W3[1]*X[11]+W3[2]*X[12];
                break;
            case 2:
                s = W3[0]*X[11]+W3[1]*X[12]
                  + W5[2]*X[0]+W5[3]*X[1]+W5[4]*X[2]
                  + W5[1]*X[0]+W5[2]*X[1]+W5[3]*X[2]+W5[4]*X[3];
                break;
            case 3:
                s = W5[0]*X[9]+W5[1]*X[10]+W5[2]*X[11]+W5[3]*X[12]
                  + W5[0]*X[10]+W5[1]*X[11]+W5[2]*X[12]
                  + W7[3]*X[0]+W7[4]*X[1]+W7[5]*X[2]+W7[6]*X[3];
                break;
            case 4:
                s = W7[2]*X[0]+W7[3]*X[1]+W7[4]*X[2]+W7[5]*X[3]+W7[6]*X[4]
                  + W7[1]*X[0]+W7[2]*X[1]+W7[3]*X[2]+W7[4]*X[3]+W7[5]*X[4]+W7[6]*X[5]
                  + W7[0]*X[0]+W7[1]*X[1]+W7[2]*X[2]+W7[3]*X[3]+W7[4]*X[4]+W7[5]*X[5]+W7[6]*X[6];
                break;
            default:
                s = W7[0]*X[7]+W7[1]*X[8]+W7[2]*X[9]+W7[3]*X[10]+W7[4]*X[11]+W7[5]*X[12]
                  + W7[0]*X[8]+W7[1]*X[9]+W7[2]*X[10]+W7[3]*X[11]+W7[4]*X[12]
                  + W7[0]*X[9]+W7[1]*X[10]+W7[2]*X[11]+W7[3]*X[12];
                break;
            }
            const float v = fmaxf(fmaf(s, sbn3[lnn][0], sbn3[lnn][1]), 0.f);
            term[lnn][tix][h * CH_ + cl] = v * sws3[lnn][h * CH_ + cl];
        }

        // ---- main loop over this half's channels (barrier-free) ----
        if (act) {
            float ck[29];
            #pragma unroll
            for (int t2 = 0; t2 < 29; ++t2) ck[t2] = ckl[rr][ln][t2];
            const float sc3 = sbn3[ln][0], bi = sbn3[ln][1];

            #pragma unroll 1
            for (int c = 0; c < CH_; ++c) {
                const float (*bw)[PQ_] = pl[c];
                float f0[16], f1[16], f2[16];
                float s0 = 0.f, s1 = 0.f, s2 = 0.f, s3 = 0.f;
                if (rr == 0) {
                    LOADP(f0, 2, 0)    TAPS(f0, 3, 0, 10)
                    LOADP(f1, 0, 4)    TAPS(f1, 0, 1, 10)
                    LOADP(f2, 1, 4)    TAPS(f2, 0, 2, 9)
                } else if (rr == 1) {
                    LOADP(f0, 1, -332) TAPS(f0, 2, 0, 10)
                    LOADP(f1, 2, -332) TAPS(f1, 2, 1, 10)
                    LOADP(f2, 0, -332) TAPS(f2, 3, 2, 9)
                } else {
                    LOADP(f0, 0, -664) TAPS(f0, 1, 0, 10)
                    LOADP(f1, 1, -664) TAPS(f1, 1, 1, 10)
                    LOADP(f2, 2, -664) TAPS(f2, 1, 2, 9)
                }
                const float sw = sws3[ln][h * CH_ + c];
                acc0 += fmaxf(fmaf(s0, sc3, bi), 0.f) * sw;
                acc1 += fmaxf(fmaf(s1, sc3, bi), 0.f) * sw;
                acc2 += fmaxf(fmaf(s2, sc3, bi), 0.f) * sw;
                acc3 += fmaxf(fmaf(s3, sc3, bi), 0.f) * sw;
            }
        }
        __syncthreads();   // S3: all pl reads done; next half may restage
    }

    // ---- hrow writes + corr reduce ----
    if (act) *(float4*)&hrow[ln][4*tile] = make_float4(acc0, acc1, acc2, acc3);
    if (tid < 18) {
        const int lnn = tid / 6, tix = tid % 6;
        float s = 0.f;
        for (int c = 0; c < C_; ++c) s += term[lnn][tix][c];
        corr[lnn][tix] = s;
    }
    __syncthreads();
    if (tid < 18) {    // substitute exact special outputs
        const int lnn = tid / 6, tix = tid % 6;
        const int t = (tix == 0) ? 0 :
                      (tix <= 2) ? (331 + tix) :        // 332, 333
                      (tix <= 4) ? (663 + tix) : 999;   // 666, 667
        hrow[lnn][t] = corr[lnn][tix];
    }
    __syncthreads();

    // ---- pooling: 24 windows x 8 threads ----
    if (tid < 192) {
        const int w = tid >> 3, jj = tid & 7;
        const int lnn = w >> 3, p = w & 7;
        float s = 0.f;
        for (int k = jj; k < POOL_; k += 8) s += hrow[lnn][p*POOL_ + k];
        s += __shfl_down(s, 4, 8);
        s += __shfl_down(s, 2, 8);
        s += __shfl_down(s, 1, 8);
        if (jj == 0) {
            psum[w] = s;
            hp[(b*NB_ + nbb + lnn)*TP_ + p] = s * (1.f / POOL_);
        }
    }
    __syncthreads();
    if (tid < 3) {
        float s = 0.f;
        for (int p = 0; p < TP_; ++p) s += psum[tid*TP_ + p];
        gm[b*NB_ + nbb + tid] = s * (1.f / T_);
    }
}

// ---------------------------------------------------------------------------
// Stage 2 (proven R5 kernel): gate (softmax + top-3 + renorm), experts +
// EBN + ReLU + mix, FC + log_softmax. One block (64 thr) per batch element.
// ---------------------------------------------------------------------------
__global__ __launch_bounds__(64) void fb_stage2(
    const float* __restrict__ hp, const float* __restrict__ gm,
    const float* __restrict__ gate_w, const float* __restrict__ gate_b,
    const float* __restrict__ exp_w,  const float* __restrict__ exp_b,
    const float* __restrict__ ebn_g,  const float* __restrict__ ebn_b,
    const float* __restrict__ ebn_m,  const float* __restrict__ ebn_v,
    const float* __restrict__ fc_w,   const float* __restrict__ fc_b,
    float* __restrict__ feats_out, float* __restrict__ logp_out)
{
    const int b   = blockIdx.x;
    const int tid = threadIdx.x;

    __shared__ float lg[MNB_];
    __shared__ float gsh[E_];
    __shared__ float hps[MNB_];
    __shared__ float fsh[FEAT_];
    __shared__ float lo[NC_];

    if (tid < MNB_) {
        hps[tid] = hp[b*MNB_ + tid];
        float s = gate_b[tid];
        for (int c = 0; c < NB_; ++c) s += gm[b*NB_ + c] * gate_w[tid*NB_ + c];
        lg[tid] = s;
    }
    __syncthreads();

    if (tid == 0) {
        float mx = lg[0];
        for (int i = 1; i < MNB_; ++i) mx = fmaxf(mx, lg[i]);
        for (int i = 0; i < MNB_; ++i) lg[i] = expf(lg[i] - mx);
        int i1 = 0, i2 = -1, i3 = -1;
        float b1 = -1.f, b2 = -1.f, b3 = -1.f;
        for (int i = 0; i < MNB_; ++i) if (lg[i] > b1) { b1 = lg[i]; i1 = i; }
        for (int i = 0; i < MNB_; ++i) if (i != i1 && lg[i] > b2) { b2 = lg[i]; i2 = i; }
        for (int i = 0; i < MNB_; ++i) if (i != i1 && i != i2 && lg[i] > b3) { b3 = lg[i]; i3 = i; }
        const float s3 = lg[i1] + lg[i2] + lg[i3];
        for (int jj = 0; jj < E_; ++jj) gsh[jj] = 0.f;
        if (i1 < E_) gsh[i1] = lg[i1] / s3;
        if (i2 < E_) gsh[i2] = lg[i2] / s3;
        if (i3 < E_) gsh[i3] = lg[i3] / s3;
    }
    __syncthreads();

    #pragma unroll
    for (int rrr = 0; rrr < FEAT_/64; ++rrr) {
        const int idx = tid + rrr*64;       // 0..383
        const int o = idx >> 3, p = idx & 7;
        float outv = 0.f;
        #pragma unroll
        for (int e = 0; e < E_; ++e) {
            const int eo = e*MNB_ + o;
            float acc = exp_b[eo];
            #pragma unroll
            for (int c = 0; c < NB_; ++c)
                acc += hps[c*TP_ + p] * exp_w[eo*NB_ + c];
            const float esc = ebn_g[eo] * rsqrtf(ebn_v[eo] + 1e-5f);
            float v = fmaf(acc - ebn_m[eo], esc, ebn_b[eo]);
            v = fmaxf(v, 0.f);
            outv += gsh[e] * v;
        }
        fsh[idx] = outv;
        feats_out[b*FEAT_ + idx] = outv;
    }
    __syncthreads();

    if (tid < NC_) {
        float s = fc_b[tid];
        for (int i = 0; i < FEAT_; ++i) s += fsh[i] * fc_w[tid*FEAT_ + i];
        lo[tid] = s;
    }
    __syncthreads();

    if (tid == 0) {
        float mx = lo[0];
        for (int k = 1; k < NC_; ++k) mx = fmaxf(mx, lo[k]);
        float Z = 0.f;
        for (int k = 0; k < NC_; ++k) Z += expf(lo[k] - mx);
        const float lse = mx + logf(Z);
        for (int k = 0; k < NC_; ++k) logp_out[b*NC_ + k] = lo[k] - lse;
    }
}

extern "C" void kernel_launch(void* const* d_in, const int* in_sizes, int n_in,
                              void* d_out, int out_size, void* d_ws, size_t ws_size,
                              hipStream_t stream) {
    const float* x       = (const float*)d_in[0];
    const float* fir     = (const float*)d_in[1];
    const float* w3      = (const float*)d_in[2];
    const float* w5      = (const float*)d_in[3];
    const float* w7      = (const float*)d_in[4];
    const float* bn1_g   = (const float*)d_in[5];
    const float* bn1_b   = (const float*)d_in[6];
    const float* bn1_m   = (const float*)d_in[7];
    const float* bn1_v   = (const float*)d_in[8];
    const float* sconv_w = (const float*)d_in[9];
    const float* gate_w  = (const float*)d_in[10];
    const float* gate_b  = (const float*)d_in[11];
    const float* exp_w   = (const float*)d_in[12];
    const float* exp_b   = (const float*)d_in[13];
    const float* ebn_g   = (const float*)d_in[14];
    const float* ebn_b   = (const float*)d_in[15];
    const float* ebn_m   = (const float*)d_in[16];
    const float* ebn_v   = (const float*)d_in[17];
    const float* fc_w    = (const float*)d_in[18];
    const float* fc_b    = (const float*)d_in[19];

    float* out       = (float*)d_out;
    float* feats_out = out;                     // (256, 384)
    float* logp_out  = out + B_ * FEAT_;        // (256, 9)

    float* hp  = (float*)d_ws;                  // (256, 48)
    float* gmv = hp + B_ * MNB_;                // (256, 6)

    fb_stage1<<<2 * B_, NTH, 0, stream>>>(x, fir, w3, w5, w7,
                                          bn1_g, bn1_b, bn1_m, bn1_v,
                                          sconv_w, hp, gmv);
    fb_stage2<<<B_, 64, 0, stream>>>(hp, gmv, gate_w, gate_b,
                                     exp_w, exp_b, ebn_g, ebn_b, ebn_m, ebn_v,
                                     fc_w, fc_b, feats_out, logp_out);
}